// Round 8
// baseline (211.563 us; speedup 1.0000x reference)
//
#include <hip/hip_runtime.h>
#include <stdint.h>

// Problem constants (match reference)
#define Bn   256
#define Dn   2048
#define Sn   8
#define ON   1000

// Tiling
#define ROWS 64             // max samples per subject (binomial mean 32; 6+ sigma)
#define OT   256            // o per block (4 oc blocks; oc=3 ragged, clamped)
#define KS   256            // k per block
#define NDC  (Dn / KS)      // 8 part slices / kc blocks per (oc,s) group
#define STK  32             // k per sub-tile
#define NST  (KS / STK)     // 8 sub-tiles, double-buffered LDS, depth-3 W ring
#define LDKS 40             // shorts per o-row: 32 k + 8 pad = 80B (16B multiple)
#define BUFB (OT * LDKS * 2) // bytes per LDS buffer = 20480
#define MAGIC 0x13579BDFu   // completion flag value (≠ plausible poison patterns)

typedef short v8s __attribute__((ext_vector_type(8)));
typedef short v4s __attribute__((ext_vector_type(4)));
typedef float v4f __attribute__((ext_vector_type(4)));

// fp32 -> bf16 round-to-nearest-even
static __device__ __forceinline__ short f2bf(float f) {
    union { float f; uint32_t u; } v; v.f = f;
    uint32_t u = v.u;
    u += 0x7FFFu + ((u >> 16) & 1u);
    return (short)(u >> 16);
}

// Single fused kernel: grid (4 oc, 8 kc, 8 s) = 256 blocks, 512 threads.
// GEMM body = R6-proven structure (1KB-contiguous W wave-loads, register
// 4o x 4k transpose -> granule-XOR-swizzled [o][k] bf16 LDS, depth-3 W ring,
// one raw s_barrier + lgkmcnt(0) per 32-k sub-tile, vmcnt never drained).
// NEW: the reduce kernel is FUSED via a device-scope flag handshake — the 8
// kc-blocks of each (oc,s) group signal part-write completion (threadfence
// release + atomicExch MAGIC), all 8 poll the group's flags, then each
// reduces 1/8 of the group's o-range (thread = (row, float4-slot)) straight
// into out with bias. Saves the reduce launch + gap (~5 us). Flags live in
// the poisoned workspace: first use after poison blocks correctly; stale-
// MAGIC replays read the previous identical iteration's values (benign).
__global__ __launch_bounds__(512) void main_kernel(const float* __restrict__ x,
                                                   const int* __restrict__ sid,
                                                   const float* __restrict__ W,
                                                   const float* __restrict__ bias,
                                                   float* __restrict__ part,
                                                   unsigned int* __restrict__ flags,
                                                   float* __restrict__ out) {
    __shared__ unsigned short Bsh[2][OT * LDKS];   // 2 x 20KB
    __shared__ unsigned long long bmask[8];
    __shared__ int rows_l[ROWS];

    const int oc = blockIdx.x;   // 0..3
    const int kc = blockIdx.y;   // 0..7
    const int s  = blockIdx.z;   // 0..7
    const int o0 = oc * OT;
    const int k0 = kc * KS;
    const int t  = threadIdx.x;
    const int lane = t & 63;
    const int w    = t >> 6;     // 0..7

    // ---- bucket samples of subject s via ballot (prefix-dense rows_l) ----
    const int mysid = (t < Bn) ? sid[t] : -1;
    const bool match = (mysid == s);
    const unsigned long long m = __ballot(match);
    if (lane == 0) bmask[w] = m;
    if (t < ROWS) rows_l[t] = -1;
    __syncthreads();
    if (match) {
        int pos = __popcll(m & ((1ull << lane) - 1ull));
        for (int ww = 0; ww < w; ++ww) pos += __popcll(bmask[ww]);
        if (pos < ROWS) rows_l[pos] = t;
    }
    __syncthreads();

    // ---- W staging geometry: wave w covers k-rows 4w..4w+3 of each sub-tile;
    //      lane covers o = o0 + 4*lane .. +3 (contiguous 1KB per wave-instr) ----
    int og = o0 + 4 * lane;
    if (og > ON - 4) og = ON - 4;               // oc=3 ragged: duplicate loads, local col kept
    const float* wpb = W + ((size_t)s * Dn + k0 + 4 * w) * ON + og;

    // LDS write addrs (buffer 0): b64 of k=4w..4w+3 at o=4*lane+i.
    // byte = o*80 + 16*((w>>1) ^ (lane&3)) + 8*(w&1)   [granule-XOR swizzle]
    unsigned short* wr[4];
#pragma unroll
    for (int i = 0; i < 4; ++i)
        wr[i] = (unsigned short*)((char*)&Bsh[0][0]
                + (4 * lane + i) * 80 + 16 * ((w >> 1) ^ (lane & 3)) + 8 * (w & 1));

    // ---- A geometry: wave w -> rows (w>>1)*16..+15, o-half (w&1) ----
    const int lo16 = lane & 15;
    const int quad = lane >> 4;
    const int arow = (w >> 1) * 16 + lo16;
    const int xrow = rows_l[arow];
    const bool wactive = (rows_l[(w >> 1) * 16] >= 0);    // prefix-dense
    const float* xp = (xrow >= 0 ? x + (size_t)xrow * Dn : x) + k0 + quad * 8;

    // ---- A loads issued FIRST (L2/L3-resident x, oldest in vmcnt order so
    //      waiting on them never drains the younger W stream) ----
    float4 a0[NST], a1[NST];
#pragma unroll
    for (int st = 0; st < NST; ++st) {
        a0[st] = *(const float4*)(xp + st * STK);
        a1[st] = *(const float4*)(xp + st * STK + 4);
    }

    // ---- W prologue: issue sub-tiles 0,1,2 (depth-3 ring, 48 VGPRs) ----
    v4f fb[3][4];
#pragma unroll
    for (int c = 0; c < 3; ++c)
#pragma unroll
        for (int r = 0; r < 4; ++r)
            fb[c][r] = *(const v4f*)(wpb + ((size_t)c * STK + r) * ON);

    // ---- convert A to bf16 fragments (frees the 64 raw VGPRs) ----
    v8s af[NST];
#pragma unroll
    for (int st = 0; st < NST; ++st) {
        v8s a;
        a[0] = f2bf(a0[st].x); a[1] = f2bf(a0[st].y);
        a[2] = f2bf(a0[st].z); a[3] = f2bf(a0[st].w);
        a[4] = f2bf(a1[st].x); a[5] = f2bf(a1[st].y);
        a[6] = f2bf(a1[st].z); a[7] = f2bf(a1[st].w);
        af[st] = a;
    }

    // B-frag read base: o_loc = (w&1)*128 + nt*16 + lo16; granule swizzle by lo16
    const int rb0  = (w & 1) * 128 + lo16;
    const int rswz = 16 * (quad ^ ((lo16 >> 2) & 3));

    v4f acc[8];
#pragma unroll
    for (int i = 0; i < 8; ++i) acc[i] = (v4f){0.f, 0.f, 0.f, 0.f};

    // ---- main loop: one barrier per 32-k sub-tile, counted vmcnt throughout.
    //      Fully unrolled -> fb[st%3] indices are compile-time constants. ----
#pragma unroll
    for (int st = 0; st < NST; ++st) {
        const int sl = st & 1;          // LDS buffer
        const int rg = st % 3;          // W ring slot
        // register transpose: 4o x 4k -> four b64 k-runs
#pragma unroll
        for (int i = 0; i < 4; ++i) {
            v4s kv;
            kv[0] = f2bf(fb[rg][0][i]);
            kv[1] = f2bf(fb[rg][1][i]);
            kv[2] = f2bf(fb[rg][2][i]);
            kv[3] = f2bf(fb[rg][3][i]);
            *(v4s*)((char*)wr[i] + sl * BUFB) = kv;
        }
        // issue sub-tile st+3's loads (stay in flight across the barrier)
        if (st + 3 < NST) {
#pragma unroll
            for (int r = 0; r < 4; ++r)
                fb[rg][r] = *(const v4f*)(wpb + ((size_t)(st + 3) * STK + r) * ON);
        }
        asm volatile("s_waitcnt lgkmcnt(0)" ::: "memory");
        __builtin_amdgcn_s_barrier();
        asm volatile("" ::: "memory");

        // compute sub-tile st: 8 MFMA per wave (16 rows x 128-o-half x 32k)
        if (wactive) {
            const v8s a = af[st];
            const char* bb = (const char*)&Bsh[sl][0];
#pragma unroll
            for (int nt = 0; nt < 8; ++nt) {
                const v8s bf = *(const v8s*)(bb + (rb0 + nt * 16) * 80 + rswz);
                acc[nt] = __builtin_amdgcn_mfma_f32_16x16x32_bf16(a, bf, acc[nt],
                                                                  0, 0, 0);
            }
        }
    }

    // ---- partial epilogue: C/D layout col=lane&15, row=quad*4+reg ----
    if (wactive) {
        float* pp = part + (size_t)kc * Bn * ON;
        const int er0 = (w >> 1) * 16 + quad * 4;
#pragma unroll
        for (int nt = 0; nt < 8; ++nt) {
            const int o = o0 + (w & 1) * 128 + nt * 16 + lo16;
            if (o < ON) {
#pragma unroll
                for (int r = 0; r < 4; ++r) {
                    const int bi = rows_l[er0 + r];
                    if (bi >= 0) pp[(size_t)bi * ON + o] = acc[nt][r];
                }
            }
        }
    }

    // ---- fused reduction handshake ----
    unsigned int* flg = flags + (oc * Sn + s) * NDC;
    __threadfence();                       // release: part stores visible device-wide
    __syncthreads();                       // all threads of this block have fenced
    if (t == 0) atomicExch(&flg[kc], MAGIC);
    if (t < NDC) {                         // each of 8 threads polls one group flag
        while (atomicAdd(&flg[t], 0u) != MAGIC) __builtin_amdgcn_s_sleep(8);
    }
    __syncthreads();                       // whole block sees: all 8 parts written
    __threadfence();                       // acquire: invalidate stale cache lines

    // ---- reduce 1/8 of the group's o-range: thread = (row, float4-slot).
    //      Same summation order as the old reduce kernel (bias + d=0..7). ----
    {
        const int rr = t >> 3;                         // 0..63
        const int o  = o0 + kc * 32 + (t & 7) * 4;     // this block's 32-col slice
        const int bi = rows_l[rr];
        if (bi >= 0 && o <= ON - 4) {
            float4 v = *(const float4*)(bias + (size_t)s * ON + o);
#pragma unroll
            for (int d = 0; d < NDC; ++d) {
                const float4 p = *(const float4*)(part + ((size_t)d * Bn + bi) * ON + o);
                v.x += p.x; v.y += p.y; v.z += p.z; v.w += p.w;
            }
            *(float4*)(out + (size_t)bi * ON + o) = v;
        }
    }
}

extern "C" void kernel_launch(void* const* d_in, const int* in_sizes, int n_in,
                              void* d_out, int out_size, void* d_ws, size_t ws_size,
                              hipStream_t stream) {
    const float* x    = (const float*)d_in[0];
    const int*   sid  = (const int*)d_in[1];
    const float* W    = (const float*)d_in[2];
    const float* bias = (const float*)d_in[3];
    float*       out  = (float*)d_out;
    float*       part = (float*)d_ws;   // NDC*Bn*ON floats = 8.192 MB
    unsigned int* flags = (unsigned int*)((char*)d_ws
                        + (size_t)NDC * Bn * ON * sizeof(float));  // 256 uints

    main_kernel<<<dim3(4, NDC, Sn), dim3(512), 0, stream>>>(x, sid, W, bias,
                                                            part, flags, out);
}

// Round 9
// 107.906 us; speedup vs baseline: 1.9606x; 1.9606x over previous
//
#include <hip/hip_runtime.h>
#include <stdint.h>

// Problem constants (match reference)
#define Bn   256
#define Dn   2048
#define Sn   8
#define ON   1000

// Tiling
#define ROWS 64             // max samples per subject (binomial mean 32; 6+ sigma)
#define OT   256            // o per block (4 oc blocks; oc=3 ragged, clamped)
#define KS   256            // k per block
#define NDC  (Dn / KS)      // 8 part slices
#define STK  32             // k per sub-tile
#define NST  (KS / STK)     // 8 sub-tiles, double-buffered LDS, depth-3 W ring
#define LDKS 40             // shorts per o-row in Bsh: 32 k + 8 pad = 80B (16B multiple)
#define BUFB (OT * LDKS * 2) // bytes per LDS buffer = 20480

typedef short v8s __attribute__((ext_vector_type(8)));
typedef short v4s __attribute__((ext_vector_type(4)));
typedef float v4f __attribute__((ext_vector_type(4)));

// fp32 -> bf16 round-to-nearest-even
static __device__ __forceinline__ short f2bf(float f) {
    union { float f; uint32_t u; } v; v.f = f;
    uint32_t u = v.u;
    u += 0x7FFFu + ((u >> 16) & 1u);
    return (short)(u >> 16);
}

// R6 config — verified best (106.75 us). Session ledger:
//  R5: 1KB-contiguous W wave-loads along o + register 4ox4k transpose ->
//      granule-XOR-swizzled [o][k] bf16 LDS  => the one real main-kernel win.
//  R6: drop gather (A inline from x, loads issued first) + depth-3 ring  => -2.0 us.
//  R7: barrier-free 7-buffer staging => neutral (+1.6): per-sub-tile barrier
//      lockstep was NOT a cost at 1 block/CU.
//  R8: fused reduce via threadfence+atomic flags => -105 us REGRESSION:
//      device-scope fences (L2 wb/inv, per-XCD non-coherent) + RMW polling
//      cost far more than the reduce launch gap. Separate reduce IS optimal.
// Remaining budget: 2x41us poison fills (harness-fixed) + main ~13-16
// (256KB/block / ~20-24 GB/s per-CU BW floor) + reduce ~3 + gap ~2.
__global__ __launch_bounds__(512) void main_kernel(const float* __restrict__ x,
                                                   const int* __restrict__ sid,
                                                   const float* __restrict__ W,
                                                   float* __restrict__ part) {
    __shared__ unsigned short Bsh[2][OT * LDKS];   // 2 x 20KB
    __shared__ unsigned long long bmask[8];
    __shared__ int rows_l[ROWS];

    const int oc = blockIdx.x;   // 0..3
    const int kc = blockIdx.y;   // 0..7
    const int s  = blockIdx.z;   // 0..7
    const int o0 = oc * OT;
    const int k0 = kc * KS;
    const int t  = threadIdx.x;
    const int lane = t & 63;
    const int w    = t >> 6;     // 0..7

    // ---- bucket samples of subject s via ballot (prefix-dense rows_l) ----
    const int mysid = (t < Bn) ? sid[t] : -1;
    const bool match = (mysid == s);
    const unsigned long long m = __ballot(match);
    if (lane == 0) bmask[w] = m;
    if (t < ROWS) rows_l[t] = -1;
    __syncthreads();
    if (match) {
        int pos = __popcll(m & ((1ull << lane) - 1ull));
        for (int ww = 0; ww < w; ++ww) pos += __popcll(bmask[ww]);
        if (pos < ROWS) rows_l[pos] = t;
    }
    __syncthreads();

    // ---- W staging geometry: wave w covers k-rows 4w..4w+3 of each sub-tile;
    //      lane covers o = o0 + 4*lane .. +3 (contiguous 1KB per wave-instr) ----
    int og = o0 + 4 * lane;
    if (og > ON - 4) og = ON - 4;               // oc=3 ragged: duplicate loads, local col kept
    const float* wpb = W + ((size_t)s * Dn + k0 + 4 * w) * ON + og;

    // LDS write addrs (buffer 0): b64 of k=4w..4w+3 at o=4*lane+i.
    // byte = o*80 + 16*((w>>1) ^ (lane&3)) + 8*(w&1)   [granule-XOR swizzle]
    unsigned short* wr[4];
#pragma unroll
    for (int i = 0; i < 4; ++i)
        wr[i] = (unsigned short*)((char*)&Bsh[0][0]
                + (4 * lane + i) * 80 + 16 * ((w >> 1) ^ (lane & 3)) + 8 * (w & 1));

    // ---- A geometry: wave w -> rows (w>>1)*16..+15, o-half (w&1) ----
    const int lo16 = lane & 15;
    const int quad = lane >> 4;
    const int arow = (w >> 1) * 16 + lo16;
    const int xrow = rows_l[arow];
    const bool wactive = (rows_l[(w >> 1) * 16] >= 0);    // prefix-dense
    const float* xp = (xrow >= 0 ? x + (size_t)xrow * Dn : x) + k0 + quad * 8;

    // ---- A loads issued FIRST (L2/L3-resident x, oldest in vmcnt order so
    //      waiting on them never drains the younger W stream) ----
    float4 a0[NST], a1[NST];
#pragma unroll
    for (int st = 0; st < NST; ++st) {
        a0[st] = *(const float4*)(xp + st * STK);
        a1[st] = *(const float4*)(xp + st * STK + 4);
    }

    // ---- W prologue: issue sub-tiles 0,1,2 (depth-3 ring, 48 VGPRs) ----
    v4f fb[3][4];
#pragma unroll
    for (int c = 0; c < 3; ++c)
#pragma unroll
        for (int r = 0; r < 4; ++r)
            fb[c][r] = *(const v4f*)(wpb + ((size_t)c * STK + r) * ON);

    // ---- convert A to bf16 fragments (frees the 64 raw VGPRs) ----
    v8s af[NST];
#pragma unroll
    for (int st = 0; st < NST; ++st) {
        v8s a;
        a[0] = f2bf(a0[st].x); a[1] = f2bf(a0[st].y);
        a[2] = f2bf(a0[st].z); a[3] = f2bf(a0[st].w);
        a[4] = f2bf(a1[st].x); a[5] = f2bf(a1[st].y);
        a[6] = f2bf(a1[st].z); a[7] = f2bf(a1[st].w);
        af[st] = a;
    }

    // B-frag read base: o_loc = (w&1)*128 + nt*16 + lo16; granule swizzle by lo16
    const int rb0  = (w & 1) * 128 + lo16;
    const int rswz = 16 * (quad ^ ((lo16 >> 2) & 3));

    v4f acc[8];
#pragma unroll
    for (int i = 0; i < 8; ++i) acc[i] = (v4f){0.f, 0.f, 0.f, 0.f};

    // ---- main loop: one barrier per 32-k sub-tile, counted vmcnt throughout.
    //      Fully unrolled -> fb[st%3] indices are compile-time constants. ----
#pragma unroll
    for (int st = 0; st < NST; ++st) {
        const int sl = st & 1;          // LDS buffer
        const int rg = st % 3;          // W ring slot
        // register transpose: 4o x 4k -> four b64 k-runs
#pragma unroll
        for (int i = 0; i < 4; ++i) {
            v4s kv;
            kv[0] = f2bf(fb[rg][0][i]);
            kv[1] = f2bf(fb[rg][1][i]);
            kv[2] = f2bf(fb[rg][2][i]);
            kv[3] = f2bf(fb[rg][3][i]);
            *(v4s*)((char*)wr[i] + sl * BUFB) = kv;
        }
        // issue sub-tile st+3's loads (stay in flight across the barrier)
        if (st + 3 < NST) {
#pragma unroll
            for (int r = 0; r < 4; ++r)
                fb[rg][r] = *(const v4f*)(wpb + ((size_t)(st + 3) * STK + r) * ON);
        }
        asm volatile("s_waitcnt lgkmcnt(0)" ::: "memory");
        __builtin_amdgcn_s_barrier();
        asm volatile("" ::: "memory");

        // compute sub-tile st: 8 MFMA per wave (16 rows x 128-o-half x 32k)
        if (wactive) {
            const v8s a = af[st];
            const char* bb = (const char*)&Bsh[sl][0];
#pragma unroll
            for (int nt = 0; nt < 8; ++nt) {
                const v8s bf = *(const v8s*)(bb + (rb0 + nt * 16) * 80 + rswz);
                acc[nt] = __builtin_amdgcn_mfma_f32_16x16x32_bf16(a, bf, acc[nt],
                                                                  0, 0, 0);
            }
        }
    }

    // ---- epilogue: C/D layout col=lane&15, row=quad*4+reg ----
    if (wactive) {
        float* pp = part + (size_t)kc * Bn * ON;
        const int er0 = (w >> 1) * 16 + quad * 4;
#pragma unroll
        for (int nt = 0; nt < 8; ++nt) {
            const int o = o0 + (w & 1) * 128 + nt * 16 + lo16;
            if (o < ON) {
#pragma unroll
                for (int r = 0; r < 4; ++r) {
                    const int bi = rows_l[er0 + r];
                    if (bi >= 0) pp[(size_t)bi * ON + o] = acc[nt][r];
                }
            }
        }
    }
}

// Reduce: out[b][o] = bias[sid[b]][o] + sum_kc part[kc][b][o]  (float4 lanes)
__global__ __launch_bounds__(256) void reduce_kernel(const int* __restrict__ sid,
                                                     const float* __restrict__ bias,
                                                     const float* __restrict__ part,
                                                     float* __restrict__ out) {
    const int b = blockIdx.x;
    const int s = sid[b];
    const int o = threadIdx.x * 4;
    if (o < ON) {          // ON=1000 -> 250 active float4 lanes
        float4 v = *(const float4*)(bias + (size_t)s * ON + o);
#pragma unroll
        for (int d = 0; d < NDC; d++) {
            const float4 p = *(const float4*)(part + ((size_t)d * Bn + b) * ON + o);
            v.x += p.x; v.y += p.y; v.z += p.z; v.w += p.w;
        }
        *(float4*)(out + (size_t)b * ON + o) = v;
    }
}

extern "C" void kernel_launch(void* const* d_in, const int* in_sizes, int n_in,
                              void* d_out, int out_size, void* d_ws, size_t ws_size,
                              hipStream_t stream) {
    const float* x    = (const float*)d_in[0];
    const int*   sid  = (const int*)d_in[1];
    const float* W    = (const float*)d_in[2];
    const float* bias = (const float*)d_in[3];
    float*       out  = (float*)d_out;
    float*       part = (float*)d_ws;   // NDC*Bn*ON floats = 8.192 MB

    main_kernel<<<dim3(4, NDC, Sn), dim3(512), 0, stream>>>(x, sid, W, part);
    reduce_kernel<<<dim3(Bn), dim3(256), 0, stream>>>(sid, bias, part, out);
}